// Round 3
// baseline (365.457 us; speedup 1.0000x reference)
//
#include <hip/hip_runtime.h>

// Conv1d via implicit GEMM on MFMA f16.
// out[b,co,t] = bias[co] + sum_{ci,m} w[co,ci,m] * x[b,ci,t-32+m], t in [0,4032)
// R3: R2 structure (W global->regs, barrier-free k-loop) with the W chunk
//     stride bug fixed: q-term stride is 8192 (was 8256).

typedef _Float16 f16;
typedef _Float16 f16x8 __attribute__((ext_vector_type(8)));
typedef float f32x4 __attribute__((ext_vector_type(4)));

#define NB   16
#define CI   128
#define CO   128
#define LIN  4096
#define KW   129
#define TOUT 4032
#define UPAD 4224                 // xT rows per batch
#define XT_BYTES ((size_t)NB * UPAD * CI * 2)   // 17,301,504

__device__ __forceinline__ void gld16(void* lds, const void* g) {
    __builtin_amdgcn_global_load_lds(
        (const __attribute__((address_space(1))) unsigned int*)g,
        (__attribute__((address_space(3))) unsigned int*)lds,
        16, 0, 0);
}

// ---------------- pre-pass 1: x (f32, [b][ci][l]) -> xT (f16, [b][u][ci], swizzled) ----
// u = l + 32; rows u<32 and u>=4128 are zero. Within each 256B row, 16B chunk c
// is stored at slot c ^ (u&7)  (bank-conflict swizzle, consumed by main kernel).
__global__ __launch_bounds__(256) void xt_prep(const float* __restrict__ x,
                                               f16* __restrict__ xt) {
    __shared__ float tile[128][33];           // [ci][lcol], +1 pad
    const int b  = blockIdx.y;
    const int u0 = blockIdx.x * 32;
    const int l0 = u0 - 32;
    const int tid = threadIdx.x;
    const int col = tid & 31;
    const int cib = tid >> 5;                 // 0..7
#pragma unroll
    for (int r = 0; r < 16; ++r) {
        int ci = cib + r * 8;
        int l  = l0 + col;
        float v = 0.f;
        if (l >= 0 && l < LIN) v = x[((size_t)b * CI + ci) * LIN + l];
        tile[ci][col] = v;
    }
    __syncthreads();
#pragma unroll
    for (int it = 0; it < 2; ++it) {
        int idx  = tid + it * 256;            // 0..511 = 32 rows * 16 chunks
        int ur   = idx >> 4;
        int slot = idx & 15;
        int c    = slot ^ ((u0 + ur) & 7);    // logical chunk stored at this slot
        f16x8 v;
#pragma unroll
        for (int j = 0; j < 8; ++j) v[j] = (f16)tile[c * 8 + j][ur];
        *(f16x8*)(&xt[((size_t)b * UPAD + u0 + ur) * CI + slot * 8]) = v;
    }
}

// ---------------- pre-pass 2: w (f32, [co][ci][m]) -> wT (f16, [kk][co][32ci]) -------
// kk = m*4 + cic. Plain layout (no swizzle): main kernel reads W straight to regs.
__global__ __launch_bounds__(256) void wt_prep(const float* __restrict__ w,
                                               f16* __restrict__ wt) {
    __shared__ float tile[32][132];           // [ci_local][m], padded
    const int cic = blockIdx.x;               // 0..3
    const int co  = blockIdx.y;               // 0..127
    const int ci0 = cic * 32;
    const int tid = threadIdx.x;
    for (int it = 0; it < 17; ++it) {
        int idx = tid + it * 256;
        if (idx < 32 * 129) {
            int i = idx / 129;
            int m = idx - i * 129;
            tile[i][m] = w[(size_t)co * (CI * KW) + (size_t)(ci0 + i) * KW + m];
        }
    }
    __syncthreads();
    for (int it = 0; it < 3; ++it) {
        int idx = tid + it * 256;
        if (idx < 129 * 4) {
            int m = idx >> 2;
            int c = idx & 3;
            int kk = m * 4 + cic;
            f16x8 v;
#pragma unroll
            for (int j = 0; j < 8; ++j) v[j] = (f16)tile[c * 8 + j][m];
            *(f16x8*)(&wt[((size_t)kk * 128 + co) * 32 + c * 8]) = v;
        }
    }
}

// ---------------- main kernel: 128co x 128t per block, 4 waves of 64x64 --------------
// LDS: xs = 256 rows x 128B (one ci-half of the x tile, swizzled) = 32 KB. No LDS-W.
__global__ __launch_bounds__(256, 2) void conv_main(
    const f16* __restrict__ xt, const f16* __restrict__ wt,
    const float* __restrict__ bias, float* __restrict__ out)
{
    extern __shared__ char smem[];
    const int tid  = threadIdx.x;
    const int lane = tid & 63;
    const int wid  = tid >> 6;
    const int l15  = lane & 15;
    const int l4   = lane >> 4;
    const int wco  = (wid >> 1) << 6;     // 0 / 64
    const int wtt  = (wid & 1) << 6;      // 0 / 64

    const int tt = blockIdx.x;            // 0..31 (t-tile)
    const int b  = blockIdx.y;            // 0..15
    const int u0 = tt << 7;

    const char* xbase = (const char*)xt + ((size_t)b * UPAD + u0) * (CI * 2);
    const char* wbase = (const char*)wt;

    // per-lane W fragment offsets: row = wco+ct*16+l15, chunk = l4 (16B)
    int wrow_off[4];
#pragma unroll
    for (int ct = 0; ct < 4; ++ct)
        wrow_off[ct] = (wco + ct * 16 + l15) * 64 + l4 * 16;

    int brow[4];
#pragma unroll
    for (int st = 0; st < 4; ++st)
        brow[st] = wtt + st * 16 + l15;

    f32x4 acc[4][4];
#pragma unroll
    for (int i = 0; i < 4; ++i)
#pragma unroll
        for (int j = 0; j < 4; ++j)
            acc[i][j] = (f32x4){0.f, 0.f, 0.f, 0.f};

    for (int p = 0; p < 2; ++p) {         // ci-halves: ci in [p*64, p*64+64)
        if (p) __syncthreads();           // all waves done reading previous x half
        // stage x half: 256 rows x 128B, linear LDS dest, pre-swizzled global src
#pragma unroll
        for (int i = 0; i < 8; ++i) {
            int off   = tid * 16 + i * 4096;
            int row   = off >> 7;
            int inrow = off & 127;
            gld16(smem + off, xbase + row * 256 + p * 128 + inrow);
        }
        __syncthreads();                  // includes vmcnt(0): x half resident

        const char* wp = wbase + p * (2 * 8192);

        f16x8 af[4], an[4];
#pragma unroll
        for (int ct = 0; ct < 4; ++ct)    // prologue: s = 0
            af[ct] = *(const f16x8*)(wp + wrow_off[ct]);

#pragma unroll 2
        for (int s = 0; s < 258; ++s) {   // m = s>>1, q = s&1 (cic = 2p+q)
            // register prefetch of step s+1 (clamped redundant load at the tail)
            const int sp = (s + 1 < 258) ? s + 1 : 257;
            const int o  = (sp >> 1) * 32768 + (sp & 1) * 8192;  // kk=m*4+2p+q, 8192 B/kk
#pragma unroll
            for (int ct = 0; ct < 4; ++ct)
                an[ct] = *(const f16x8*)(wp + o + wrow_off[ct]);

            const int m  = s >> 1;
            const int cl = ((s & 1) << 2) + l4;     // x chunk in [0,8) within half

            f16x8 bf[4];
#pragma unroll
            for (int st = 0; st < 4; ++st) {
                int row  = brow[st] + m;
                int slot = cl ^ (row & 7);
                bf[st] = *(const f16x8*)(smem + (row << 7) + (slot << 4));
            }
#pragma unroll
            for (int ct = 0; ct < 4; ++ct)
#pragma unroll
                for (int st = 0; st < 4; ++st)
                    acc[ct][st] = __builtin_amdgcn_mfma_f32_16x16x32_f16(
                        af[ct], bf[st], acc[ct][st], 0, 0, 0);
#pragma unroll
            for (int ct = 0; ct < 4; ++ct)
                af[ct] = an[ct];
        }
    }

    // epilogue: D[row=co_local][col=t_local]; row=(l>>4)*4+reg, col=l&15
#pragma unroll
    for (int ct = 0; ct < 4; ++ct) {
#pragma unroll
        for (int r = 0; r < 4; ++r) {
            int co = wco + ct * 16 + l4 * 4 + r;
            float bv = bias[co];
            float* orow = out + ((size_t)b * CO + co) * TOUT;
#pragma unroll
            for (int st = 0; st < 4; ++st) {
                int t = u0 + wtt + st * 16 + l15;
                if (t < TOUT) orow[t] = acc[ct][st][r] + bv;
            }
        }
    }
}

extern "C" void kernel_launch(void* const* d_in, const int* in_sizes, int n_in,
                              void* d_out, int out_size, void* d_ws, size_t ws_size,
                              hipStream_t stream) {
    const float* x    = (const float*)d_in[0];
    const float* w    = (const float*)d_in[1];
    const float* bias = (const float*)d_in[2];
    float* out = (float*)d_out;

    f16* xt = (f16*)d_ws;                              // 17,301,504 B
    f16* wt = (f16*)((char*)d_ws + XT_BYTES);          //  4,227,072 B

    xt_prep<<<dim3(UPAD / 32, NB), 256, 0, stream>>>(x, xt);
    wt_prep<<<dim3(4, CO), 256, 0, stream>>>(w, wt);
    conv_main<<<dim3(32, NB), 256, 32768, stream>>>(xt, wt, bias, out);
}

// Round 5
// 350.649 us; speedup vs baseline: 1.0422x; 1.0422x over previous
//
#include <hip/hip_runtime.h>

// Conv1d via implicit GEMM on MFMA f16.
// out[b,co,t] = bias[co] + sum_{ci,m} w[co,ci,m] * x[b,ci,t-32+m], t in [0,4032)
// R4 (resubmit; R4 bench never ran — acquisition timeout):
//     R3 structure (W global->regs, barrier-free k-loop) with a 2-deep
//     software pipeline on the W fragments (3 rotating static buffers).

typedef _Float16 f16;
typedef _Float16 f16x8 __attribute__((ext_vector_type(8)));
typedef float f32x4 __attribute__((ext_vector_type(4)));

#define NB   16
#define CI   128
#define CO   128
#define LIN  4096
#define KW   129
#define TOUT 4032
#define UPAD 4224                 // xT rows per batch
#define XT_BYTES ((size_t)NB * UPAD * CI * 2)   // 17,301,504

__device__ __forceinline__ void gld16(void* lds, const void* g) {
    __builtin_amdgcn_global_load_lds(
        (const __attribute__((address_space(1))) unsigned int*)g,
        (__attribute__((address_space(3))) unsigned int*)lds,
        16, 0, 0);
}

// ---------------- pre-pass 1: x (f32, [b][ci][l]) -> xT (f16, [b][u][ci], swizzled) ----
// u = l + 32; rows u<32 and u>=4128 are zero. Within each 256B row, 16B chunk c
// is stored at slot c ^ (u&7)  (bank-conflict swizzle, consumed by main kernel).
__global__ __launch_bounds__(256) void xt_prep(const float* __restrict__ x,
                                               f16* __restrict__ xt) {
    __shared__ float tile[128][33];           // [ci][lcol], +1 pad
    const int b  = blockIdx.y;
    const int u0 = blockIdx.x * 32;
    const int l0 = u0 - 32;
    const int tid = threadIdx.x;
    const int col = tid & 31;
    const int cib = tid >> 5;                 // 0..7
#pragma unroll
    for (int r = 0; r < 16; ++r) {
        int ci = cib + r * 8;
        int l  = l0 + col;
        float v = 0.f;
        if (l >= 0 && l < LIN) v = x[((size_t)b * CI + ci) * LIN + l];
        tile[ci][col] = v;
    }
    __syncthreads();
#pragma unroll
    for (int it = 0; it < 2; ++it) {
        int idx  = tid + it * 256;            // 0..511 = 32 rows * 16 chunks
        int ur   = idx >> 4;
        int slot = idx & 15;
        int c    = slot ^ ((u0 + ur) & 7);    // logical chunk stored at this slot
        f16x8 v;
#pragma unroll
        for (int j = 0; j < 8; ++j) v[j] = (f16)tile[c * 8 + j][ur];
        *(f16x8*)(&xt[((size_t)b * UPAD + u0 + ur) * CI + slot * 8]) = v;
    }
}

// ---------------- pre-pass 2: w (f32, [co][ci][m]) -> wT (f16, [kk][co][32ci]) -------
// kk = m*4 + cic. Plain layout (no swizzle): main kernel reads W straight to regs.
__global__ __launch_bounds__(256) void wt_prep(const float* __restrict__ w,
                                               f16* __restrict__ wt) {
    __shared__ float tile[32][132];           // [ci_local][m], padded
    const int cic = blockIdx.x;               // 0..3
    const int co  = blockIdx.y;               // 0..127
    const int ci0 = cic * 32;
    const int tid = threadIdx.x;
    for (int it = 0; it < 17; ++it) {
        int idx = tid + it * 256;
        if (idx < 32 * 129) {
            int i = idx / 129;
            int m = idx - i * 129;
            tile[i][m] = w[(size_t)co * (CI * KW) + (size_t)(ci0 + i) * KW + m];
        }
    }
    __syncthreads();
    for (int it = 0; it < 3; ++it) {
        int idx = tid + it * 256;
        if (idx < 129 * 4) {
            int m = idx >> 2;
            int c = idx & 3;
            int kk = m * 4 + cic;
            f16x8 v;
#pragma unroll
            for (int j = 0; j < 8; ++j) v[j] = (f16)tile[c * 8 + j][m];
            *(f16x8*)(&wt[((size_t)kk * 128 + co) * 32 + c * 8]) = v;
        }
    }
}

// ---------------- main kernel: 128co x 128t per block, 4 waves of 64x64 --------------
// LDS: xs = 256 rows x 128B (one ci-half of the x tile, swizzled) = 32 KB. No LDS-W.
__global__ __launch_bounds__(256, 2) void conv_main(
    const f16* __restrict__ xt, const f16* __restrict__ wt,
    const float* __restrict__ bias, float* __restrict__ out)
{
    extern __shared__ char smem[];
    const int tid  = threadIdx.x;
    const int lane = tid & 63;
    const int wid  = tid >> 6;
    const int l15  = lane & 15;
    const int l4   = lane >> 4;
    const int wco  = (wid >> 1) << 6;     // 0 / 64
    const int wtt  = (wid & 1) << 6;      // 0 / 64

    const int tt = blockIdx.x;            // 0..31 (t-tile)
    const int b  = blockIdx.y;            // 0..15
    const int u0 = tt << 7;

    const char* xbase = (const char*)xt + ((size_t)b * UPAD + u0) * (CI * 2);
    const char* wbase = (const char*)wt;

    // per-lane W fragment offsets: row = wco+ct*16+l15, chunk = l4 (16B)
    int wrow_off[4];
#pragma unroll
    for (int ct = 0; ct < 4; ++ct)
        wrow_off[ct] = (wco + ct * 16 + l15) * 64 + l4 * 16;

    int brow[4];
#pragma unroll
    for (int st = 0; st < 4; ++st)
        brow[st] = wtt + st * 16 + l15;

    f32x4 acc[4][4];
#pragma unroll
    for (int i = 0; i < 4; ++i)
#pragma unroll
        for (int j = 0; j < 4; ++j)
            acc[i][j] = (f32x4){0.f, 0.f, 0.f, 0.f};

    for (int p = 0; p < 2; ++p) {         // ci-halves: ci in [p*64, p*64+64)
        if (p) __syncthreads();           // all waves done reading previous x half
        // stage x half: 256 rows x 128B, linear LDS dest, pre-swizzled global src
#pragma unroll
        for (int i = 0; i < 8; ++i) {
            int off   = tid * 16 + i * 4096;
            int row   = off >> 7;
            int inrow = off & 127;
            gld16(smem + off, xbase + row * 256 + p * 128 + inrow);
        }
        __syncthreads();                  // includes vmcnt(0): x half resident

        const char* wp = wbase + p * (2 * 8192);

        // 2-deep W software pipeline, 3 static rotating buffers (rule #20:
        // no runtime indexing -> stays in registers).
        f16x8 w0[4], w1[4], w2[4];
#pragma unroll
        for (int ct = 0; ct < 4; ++ct) {  // prologue: s=0 -> w0, s=1 -> w1
            w0[ct] = *(const f16x8*)(wp + wrow_off[ct]);
            w1[ct] = *(const f16x8*)(wp + 8192 + wrow_off[ct]);
        }

        auto step = [&](int s, f16x8 (&use)[4], f16x8 (&fill)[4]) {
            // issue load for step s+2 into `fill` (clamped redundant at tail)
            const int sp = (s + 2 < 258) ? s + 2 : 257;
            const int o  = (sp >> 1) * 32768 + (sp & 1) * 8192;  // kk stride 8192 B
#pragma unroll
            for (int ct = 0; ct < 4; ++ct)
                fill[ct] = *(const f16x8*)(wp + o + wrow_off[ct]);

            const int m  = s >> 1;
            const int cl = ((s & 1) << 2) + l4;   // x chunk in [0,8) within half
            f16x8 bf[4];
#pragma unroll
            for (int st = 0; st < 4; ++st) {
                int row  = brow[st] + m;
                int slot = cl ^ (row & 7);
                bf[st] = *(const f16x8*)(smem + (row << 7) + (slot << 4));
            }
#pragma unroll
            for (int ct = 0; ct < 4; ++ct)
#pragma unroll
                for (int st = 0; st < 4; ++st)
                    acc[ct][st] = __builtin_amdgcn_mfma_f32_16x16x32_f16(
                        use[ct], bf[st], acc[ct][st], 0, 0, 0);
        };

        for (int s = 0; s < 258; s += 3) {   // 258 = 3 * 86
            step(s,     w0, w2);
            step(s + 1, w1, w0);
            step(s + 2, w2, w1);
        }
    }

    // epilogue: D[row=co_local][col=t_local]; row=(l>>4)*4+reg, col=l&15
#pragma unroll
    for (int ct = 0; ct < 4; ++ct) {
#pragma unroll
        for (int r = 0; r < 4; ++r) {
            int co = wco + ct * 16 + l4 * 4 + r;
            float bv = bias[co];
            float* orow = out + ((size_t)b * CO + co) * TOUT;
#pragma unroll
            for (int st = 0; st < 4; ++st) {
                int t = u0 + wtt + st * 16 + l15;
                if (t < TOUT) orow[t] = acc[ct][st][r] + bv;
            }
        }
    }
}

extern "C" void kernel_launch(void* const* d_in, const int* in_sizes, int n_in,
                              void* d_out, int out_size, void* d_ws, size_t ws_size,
                              hipStream_t stream) {
    const float* x    = (const float*)d_in[0];
    const float* w    = (const float*)d_in[1];
    const float* bias = (const float*)d_in[2];
    float* out = (float*)d_out;

    f16* xt = (f16*)d_ws;                              // 17,301,504 B
    f16* wt = (f16*)((char*)d_ws + XT_BYTES);          //  4,227,072 B

    xt_prep<<<dim3(UPAD / 32, NB), 256, 0, stream>>>(x, xt);
    wt_prep<<<dim3(4, CO), 256, 0, stream>>>(w, wt);
    conv_main<<<dim3(32, NB), 256, 32768, stream>>>(xt, wt, bias, out);
}

// Round 6
// 329.377 us; speedup vs baseline: 1.1095x; 1.0646x over previous
//
#include <hip/hip_runtime.h>

// Conv1d via implicit GEMM on MFMA f16.
// out[b,co,t] = bias[co] + sum_{ci,m} w[co,ci,m] * x[b,ci,t-32+m], t in [0,4032)
// R6: back to LDS-staged W (R1) but with T3/T4 discipline: 3-buffer W ring,
//     counted s_waitcnt vmcnt(2) + ONE raw s_barrier per k-step (no drain).

typedef _Float16 f16;
typedef _Float16 f16x8 __attribute__((ext_vector_type(8)));
typedef float f32x4 __attribute__((ext_vector_type(4)));

#define NB   16
#define CI   128
#define CO   128
#define LIN  4096
#define KW   129
#define TOUT 4032
#define UPAD 4224                 // xT rows per batch
#define XT_BYTES ((size_t)NB * UPAD * CI * 2)   // 17,301,504
#define WLDS 32768                // W ring base in LDS (after 32 KB X half)

__device__ __forceinline__ void gld16(void* lds, const void* g) {
    __builtin_amdgcn_global_load_lds(
        (const __attribute__((address_space(1))) unsigned int*)g,
        (__attribute__((address_space(3))) unsigned int*)lds,
        16, 0, 0);
}

// ---------------- pre-pass 1: x (f32, [b][ci][l]) -> xT (f16, [b][u][ci], swizzled) ----
// u = l + 32; rows u<32 and u>=4128 are zero. Within each 256B row, 16B chunk c
// is stored at slot c ^ (u&7)  (bank-conflict swizzle, consumed by main kernel).
__global__ __launch_bounds__(256) void xt_prep(const float* __restrict__ x,
                                               f16* __restrict__ xt) {
    __shared__ float tile[128][33];           // [ci][lcol], +1 pad
    const int b  = blockIdx.y;
    const int u0 = blockIdx.x * 32;
    const int l0 = u0 - 32;
    const int tid = threadIdx.x;
    const int col = tid & 31;
    const int cib = tid >> 5;                 // 0..7
#pragma unroll
    for (int r = 0; r < 16; ++r) {
        int ci = cib + r * 8;
        int l  = l0 + col;
        float v = 0.f;
        if (l >= 0 && l < LIN) v = x[((size_t)b * CI + ci) * LIN + l];
        tile[ci][col] = v;
    }
    __syncthreads();
#pragma unroll
    for (int it = 0; it < 2; ++it) {
        int idx  = tid + it * 256;            // 0..511 = 32 rows * 16 chunks
        int ur   = idx >> 4;
        int slot = idx & 15;
        int c    = slot ^ ((u0 + ur) & 7);    // logical chunk stored at this slot
        f16x8 v;
#pragma unroll
        for (int j = 0; j < 8; ++j) v[j] = (f16)tile[c * 8 + j][ur];
        *(f16x8*)(&xt[((size_t)b * UPAD + u0 + ur) * CI + slot * 8]) = v;
    }
}

// ---------------- pre-pass 2: w (f32, [co][ci][m]) -> wT (f16, [kk][co][32ci], swizzled)
// kk = m*4 + cic.  Within each 64B row, 16B chunk c stored at slot c ^ ((co>>1)&3).
__global__ __launch_bounds__(256) void wt_prep(const float* __restrict__ w,
                                               f16* __restrict__ wt) {
    __shared__ float tile[32][132];           // [ci_local][m], padded
    const int cic = blockIdx.x;               // 0..3
    const int co  = blockIdx.y;               // 0..127
    const int ci0 = cic * 32;
    const int tid = threadIdx.x;
    for (int it = 0; it < 17; ++it) {
        int idx = tid + it * 256;
        if (idx < 32 * 129) {
            int i = idx / 129;
            int m = idx - i * 129;
            tile[i][m] = w[(size_t)co * (CI * KW) + (size_t)(ci0 + i) * KW + m];
        }
    }
    __syncthreads();
    const int swz = (co >> 1) & 3;
    for (int it = 0; it < 3; ++it) {
        int idx = tid + it * 256;
        if (idx < 129 * 4) {
            int m = idx >> 2;
            int c = idx & 3;
            int kk = m * 4 + cic;
            int slot = c ^ swz;
            f16x8 v;
#pragma unroll
            for (int j = 0; j < 8; ++j) v[j] = (f16)tile[c * 8 + j][m];
            *(f16x8*)(&wt[((size_t)kk * 128 + co) * 32 + slot * 8]) = v;
        }
    }
}

// ---------------- main kernel: 128co x 128t per block, 4 waves of 64x64 --------------
// LDS: xs = 256 rows x 128B (one ci-half, swizzled) = 32 KB
//      W ring = 3 x 8 KB                            = 24 KB   (56 KB total)
__global__ __launch_bounds__(256, 2) void conv_main(
    const f16* __restrict__ xt, const f16* __restrict__ wt,
    const float* __restrict__ bias, float* __restrict__ out)
{
    extern __shared__ char smem[];
    const int tid  = threadIdx.x;
    const int lane = tid & 63;
    const int wid  = tid >> 6;
    const int l15  = lane & 15;
    const int l4   = lane >> 4;
    const int wco  = (wid >> 1) << 6;     // 0 / 64
    const int wtt  = (wid & 1) << 6;      // 0 / 64

    const int tt = blockIdx.x;            // 0..31 (t-tile)
    const int b  = blockIdx.y;            // 0..15
    const int u0 = tt << 7;

    const char* xbase = (const char*)xt + ((size_t)b * UPAD + u0) * (CI * 2);
    const char* wbase = (const char*)wt;

    // A-fragment LDS offsets within a W buffer: row = wco+ct*16+l15 (64 B rows),
    // 16B slot = l4 ^ ((co>>1)&3) = l4 ^ ((l15>>1)&3)
    const int aslotx = (l4 ^ ((l15 >> 1) & 3)) << 4;
    int aoff[4];
#pragma unroll
    for (int ct = 0; ct < 4; ++ct)
        aoff[ct] = ((wco + ct * 16 + l15) << 6) + aslotx;

    int brow[4];
#pragma unroll
    for (int st = 0; st < 4; ++st)
        brow[st] = wtt + st * 16 + l15;

    f32x4 acc[4][4];
#pragma unroll
    for (int i = 0; i < 4; ++i)
#pragma unroll
        for (int j = 0; j < 4; ++j)
            acc[i][j] = (f32x4){0.f, 0.f, 0.f, 0.f};

    for (int p = 0; p < 2; ++p) {         // ci-halves: ci in [p*64, p*64+64)
        const int pbase = 2 * p;

        __builtin_amdgcn_s_barrier();     // all waves done with previous half's LDS
        // stage x half: 256 rows x 128B, linear LDS dest, pre-swizzled global src
#pragma unroll
        for (int i = 0; i < 8; ++i) {
            int off   = tid * 16 + i * 4096;
            int row   = off >> 7;
            int inrow = off & 127;
            gld16(smem + off, xbase + row * 256 + p * 128 + inrow);
        }
        // stage W chunk (kk = 2p) into ring buf 0
        {
            const char* wsrc = wbase + (size_t)pbase * 8192;
            gld16(smem + WLDS + tid * 16,        wsrc + tid * 16);
            gld16(smem + WLDS + 4096 + tid * 16, wsrc + 4096 + tid * 16);
        }
        asm volatile("s_waitcnt vmcnt(0)" ::: "memory");
        __builtin_amdgcn_s_barrier();

        // one k-step: read W from ring buf `rb`, prefetch chunk s+1 into `pb`
        auto kstep = [&](int s, int rb, int pb, bool pf) {
            if (pf) {
                const int sp = s + 1;
                const int kk = (sp >> 1) * 4 + pbase + (sp & 1);
                const char* wsrc = wbase + (size_t)kk * 8192;
                gld16(smem + WLDS + pb * 8192 + tid * 16,        wsrc + tid * 16);
                gld16(smem + WLDS + pb * 8192 + 4096 + tid * 16, wsrc + 4096 + tid * 16);
                asm volatile("s_waitcnt vmcnt(2)" ::: "memory");   // chunk s resident
            } else {
                asm volatile("s_waitcnt vmcnt(0)" ::: "memory");
            }
            __builtin_amdgcn_s_barrier();  // everyone's chunk-s DMA landed

            const int m  = s >> 1;
            const int cl = ((s & 1) << 2) + l4;   // x chunk in [0,8) within half
            const char* wlds = smem + WLDS + rb * 8192;
            f16x8 af[4], bf[4];
#pragma unroll
            for (int ct = 0; ct < 4; ++ct)
                af[ct] = *(const f16x8*)(wlds + aoff[ct]);
#pragma unroll
            for (int st = 0; st < 4; ++st) {
                int row  = brow[st] + m;
                int slot = cl ^ (row & 7);
                bf[st] = *(const f16x8*)(smem + (row << 7) + (slot << 4));
            }
#pragma unroll
            for (int ct = 0; ct < 4; ++ct)
#pragma unroll
                for (int st = 0; st < 4; ++st)
                    acc[ct][st] = __builtin_amdgcn_mfma_f32_16x16x32_f16(
                        af[ct], bf[st], acc[ct][st], 0, 0, 0);
        };

        for (int g = 0; g < 85; ++g) {    // s = 0 .. 254
            int s = g * 3;
            kstep(s,     0, 1, true);
            kstep(s + 1, 1, 2, true);
            kstep(s + 2, 2, 0, true);
        }
        kstep(255, 0, 1, true);
        kstep(256, 1, 2, true);
        kstep(257, 2, 0, false);          // tail: drain
    }

    // epilogue: D[row=co_local][col=t_local]; row=(l>>4)*4+reg, col=l&15
#pragma unroll
    for (int ct = 0; ct < 4; ++ct) {
#pragma unroll
        for (int r = 0; r < 4; ++r) {
            int co = wco + ct * 16 + l4 * 4 + r;
            float bv = bias[co];
            float* orow = out + ((size_t)b * CO + co) * TOUT;
#pragma unroll
            for (int st = 0; st < 4; ++st) {
                int t = u0 + wtt + st * 16 + l15;
                if (t < TOUT) orow[t] = acc[ct][st][r] + bv;
            }
        }
    }
}

extern "C" void kernel_launch(void* const* d_in, const int* in_sizes, int n_in,
                              void* d_out, int out_size, void* d_ws, size_t ws_size,
                              hipStream_t stream) {
    const float* x    = (const float*)d_in[0];
    const float* w    = (const float*)d_in[1];
    const float* bias = (const float*)d_in[2];
    float* out = (float*)d_out;

    f16* xt = (f16*)d_ws;                              // 17,301,504 B
    f16* wt = (f16*)((char*)d_ws + XT_BYTES);          //  4,227,072 B

    xt_prep<<<dim3(UPAD / 32, NB), 256, 0, stream>>>(x, xt);
    wt_prep<<<dim3(4, CO), 256, 0, stream>>>(w, wt);
    conv_main<<<dim3(32, NB), 256, 57344, stream>>>(xt, wt, bias, out);
}

// Round 7
// 318.812 us; speedup vs baseline: 1.1463x; 1.0331x over previous
//
#include <hip/hip_runtime.h>

// Conv1d via implicit GEMM on MFMA f16.
// out[b,co,t] = bias[co] + sum_{ci,m} w[co,ci,m] * x[b,ci,t-32+m], t in [0,4032)
// R7: R6 + one-step-ahead LDS->reg fragment prefetch (af/bf for step j+1 read
//     during step j, overlapping step j's MFMAs). W ring deepened to 4 bufs;
//     vmcnt(2) certifies own chunks <= j+1 at each barrier. Tail drains.

typedef _Float16 f16;
typedef _Float16 f16x8 __attribute__((ext_vector_type(8)));
typedef float f32x4 __attribute__((ext_vector_type(4)));

#define NB   16
#define CI   128
#define CO   128
#define LIN  4096
#define KW   129
#define TOUT 4032
#define UPAD 4224                 // xT rows per batch
#define XT_BYTES ((size_t)NB * UPAD * CI * 2)   // 17,301,504
#define WLDS 32768                // W ring base in LDS (after 32 KB X half)

__device__ __forceinline__ void gld16(void* lds, const void* g) {
    __builtin_amdgcn_global_load_lds(
        (const __attribute__((address_space(1))) unsigned int*)g,
        (__attribute__((address_space(3))) unsigned int*)lds,
        16, 0, 0);
}

// ---------------- pre-pass 1: x (f32, [b][ci][l]) -> xT (f16, [b][u][ci], swizzled) ----
// u = l + 32; rows u<32 and u>=4128 are zero. Within each 256B row, 16B chunk c
// is stored at slot c ^ (u&7)  (bank-conflict swizzle, consumed by main kernel).
__global__ __launch_bounds__(256) void xt_prep(const float* __restrict__ x,
                                               f16* __restrict__ xt) {
    __shared__ float tile[128][33];           // [ci][lcol], +1 pad
    const int b  = blockIdx.y;
    const int u0 = blockIdx.x * 32;
    const int l0 = u0 - 32;
    const int tid = threadIdx.x;
    const int col = tid & 31;
    const int cib = tid >> 5;                 // 0..7
#pragma unroll
    for (int r = 0; r < 16; ++r) {
        int ci = cib + r * 8;
        int l  = l0 + col;
        float v = 0.f;
        if (l >= 0 && l < LIN) v = x[((size_t)b * CI + ci) * LIN + l];
        tile[ci][col] = v;
    }
    __syncthreads();
#pragma unroll
    for (int it = 0; it < 2; ++it) {
        int idx  = tid + it * 256;            // 0..511 = 32 rows * 16 chunks
        int ur   = idx >> 4;
        int slot = idx & 15;
        int c    = slot ^ ((u0 + ur) & 7);    // logical chunk stored at this slot
        f16x8 v;
#pragma unroll
        for (int j = 0; j < 8; ++j) v[j] = (f16)tile[c * 8 + j][ur];
        *(f16x8*)(&xt[((size_t)b * UPAD + u0 + ur) * CI + slot * 8]) = v;
    }
}

// ---------------- pre-pass 2: w (f32, [co][ci][m]) -> wT (f16, [kk][co][32ci], swizzled)
// kk = m*4 + cic.  Within each 64B row, 16B chunk c stored at slot c ^ ((co>>1)&3).
__global__ __launch_bounds__(256) void wt_prep(const float* __restrict__ w,
                                               f16* __restrict__ wt) {
    __shared__ float tile[32][132];           // [ci_local][m], padded
    const int cic = blockIdx.x;               // 0..3
    const int co  = blockIdx.y;               // 0..127
    const int ci0 = cic * 32;
    const int tid = threadIdx.x;
    for (int it = 0; it < 17; ++it) {
        int idx = tid + it * 256;
        if (idx < 32 * 129) {
            int i = idx / 129;
            int m = idx - i * 129;
            tile[i][m] = w[(size_t)co * (CI * KW) + (size_t)(ci0 + i) * KW + m];
        }
    }
    __syncthreads();
    const int swz = (co >> 1) & 3;
    for (int it = 0; it < 3; ++it) {
        int idx = tid + it * 256;
        if (idx < 129 * 4) {
            int m = idx >> 2;
            int c = idx & 3;
            int kk = m * 4 + cic;
            int slot = c ^ swz;
            f16x8 v;
#pragma unroll
            for (int j = 0; j < 8; ++j) v[j] = (f16)tile[c * 8 + j][m];
            *(f16x8*)(&wt[((size_t)kk * 128 + co) * 32 + slot * 8]) = v;
        }
    }
}

// ---------------- main kernel: 128co x 128t per block, 4 waves of 64x64 --------------
// LDS: xs = 256 rows x 128B (one ci-half, swizzled) = 32 KB
//      W ring = 4 x 8 KB                            = 32 KB   (64 KB total)
__global__ __launch_bounds__(256, 2) void conv_main(
    const f16* __restrict__ xt, const f16* __restrict__ wt,
    const float* __restrict__ bias, float* __restrict__ out)
{
    extern __shared__ char smem[];
    const int tid  = threadIdx.x;
    const int lane = tid & 63;
    const int wid  = tid >> 6;
    const int l15  = lane & 15;
    const int l4   = lane >> 4;
    const int wco  = (wid >> 1) << 6;     // 0 / 64
    const int wtt  = (wid & 1) << 6;      // 0 / 64

    const int tt = blockIdx.x;            // 0..31 (t-tile)
    const int b  = blockIdx.y;            // 0..15
    const int u0 = tt << 7;

    const char* xbase = (const char*)xt + ((size_t)b * UPAD + u0) * (CI * 2);
    const char* wbase = (const char*)wt;
    char* wring = smem + WLDS;

    // A-fragment LDS offsets within a W buffer: row = wco+ct*16+l15 (64 B rows),
    // 16B slot = l4 ^ ((co>>1)&3) = l4 ^ ((l15>>1)&3)
    const int aslotx = (l4 ^ ((l15 >> 1) & 3)) << 4;
    int aoff[4];
#pragma unroll
    for (int ct = 0; ct < 4; ++ct)
        aoff[ct] = ((wco + ct * 16 + l15) << 6) + aslotx;

    int brow[4];
#pragma unroll
    for (int st = 0; st < 4; ++st)
        brow[st] = wtt + st * 16 + l15;

    f32x4 acc[4][4];
#pragma unroll
    for (int i = 0; i < 4; ++i)
#pragma unroll
        for (int j = 0; j < 4; ++j)
            acc[i][j] = (f32x4){0.f, 0.f, 0.f, 0.f};

    for (int p = 0; p < 2; ++p) {         // ci-halves: ci in [p*64, p*64+64)
        const int pbase = 2 * p;

        // prologue: stage X half (8 loads) + W chunks 0..2 (6 loads)
#pragma unroll
        for (int i = 0; i < 8; ++i) {
            int off   = tid * 16 + i * 4096;
            int row   = off >> 7;
            int inrow = off & 127;
            gld16(smem + off, xbase + row * 256 + p * 128 + inrow);
        }
#pragma unroll
        for (int c = 0; c < 3; ++c) {
            const int kk = (c >> 1) * 4 + pbase + (c & 1);
            const char* wsrc = wbase + (size_t)kk * 8192;
            gld16(wring + c * 8192 + tid * 16,        wsrc + tid * 16);
            gld16(wring + c * 8192 + 4096 + tid * 16, wsrc + 4096 + tid * 16);
        }
        asm volatile("s_waitcnt vmcnt(2)" ::: "memory");  // X + chunks 0,1 resident
        __builtin_amdgcn_s_barrier();                     // all waves: <=1 certified

        // preload fragments for j = 0 (m=0, cl=l4, ring buf 0)
        f16x8 afA[4], bfA[4], afB[4], bfB[4];
#pragma unroll
        for (int ct = 0; ct < 4; ++ct)
            afA[ct] = *(const f16x8*)(wring + aoff[ct]);
#pragma unroll
        for (int st = 0; st < 4; ++st) {
            int row  = brow[st];
            int slot = l4 ^ (row & 7);
            bfA[st] = *(const f16x8*)(smem + (row << 7) + (slot << 4));
        }

        // step j: MFMA uses (afC,bfC) loaded at step j-1; prefetch (afN,bfN)
        // for j+1; issue DMA for chunk j+3; vmcnt(2) certifies own <= j+1.
        auto body = [&](int j, f16x8 (&afC)[4], f16x8 (&bfC)[4],
                               f16x8 (&afN)[4], f16x8 (&bfN)[4]) {
            const bool issue = (j + 3 <= 257);
            if (issue) {
                const int kn = j + 3;
                const int kk = (kn >> 1) * 4 + pbase + (kn & 1);
                const char* wsrc = wbase + (size_t)kk * 8192;
                char* dst = wring + (kn & 3) * 8192;
                gld16(dst + tid * 16,        wsrc + tid * 16);
                gld16(dst + 4096 + tid * 16, wsrc + 4096 + tid * 16);
            }
            if (j + 1 <= 257) {
                const int jn  = j + 1;
                const int mn  = jn >> 1;
                const int cln = ((jn & 1) << 2) + l4;
                const char* wl = wring + (jn & 3) * 8192;
#pragma unroll
                for (int ct = 0; ct < 4; ++ct)
                    afN[ct] = *(const f16x8*)(wl + aoff[ct]);
#pragma unroll
                for (int st = 0; st < 4; ++st) {
                    int row  = brow[st] + mn;
                    int slot = cln ^ (row & 7);
                    bfN[st] = *(const f16x8*)(smem + (row << 7) + (slot << 4));
                }
            }
            if (issue) asm volatile("s_waitcnt vmcnt(2)" ::: "memory");
            else       asm volatile("s_waitcnt vmcnt(0)" ::: "memory");
            __builtin_amdgcn_s_barrier();
#pragma unroll
            for (int ct = 0; ct < 4; ++ct)
#pragma unroll
                for (int st = 0; st < 4; ++st)
                    acc[ct][st] = __builtin_amdgcn_mfma_f32_16x16x32_f16(
                        afC[ct], bfC[st], acc[ct][st], 0, 0, 0);
        };

        for (int jj = 0; jj < 258; jj += 2) {   // 258 steps, A/B reg ping-pong
            body(jj,     afA, bfA, afB, bfB);
            body(jj + 1, afB, bfB, afA, bfA);
        }
    }

    // epilogue: D[row=co_local][col=t_local]; row=(l>>4)*4+reg, col=l&15
#pragma unroll
    for (int ct = 0; ct < 4; ++ct) {
#pragma unroll
        for (int r = 0; r < 4; ++r) {
            int co = wco + ct * 16 + l4 * 4 + r;
            float bv = bias[co];
            float* orow = out + ((size_t)b * CO + co) * TOUT;
#pragma unroll
            for (int st = 0; st < 4; ++st) {
                int t = u0 + wtt + st * 16 + l15;
                if (t < TOUT) orow[t] = acc[ct][st][r] + bv;
            }
        }
    }
}

extern "C" void kernel_launch(void* const* d_in, const int* in_sizes, int n_in,
                              void* d_out, int out_size, void* d_ws, size_t ws_size,
                              hipStream_t stream) {
    const float* x    = (const float*)d_in[0];
    const float* w    = (const float*)d_in[1];
    const float* bias = (const float*)d_in[2];
    float* out = (float*)d_out;

    f16* xt = (f16*)d_ws;                              // 17,301,504 B
    f16* wt = (f16*)((char*)d_ws + XT_BYTES);          //  4,227,072 B

    xt_prep<<<dim3(UPAD / 32, NB), 256, 0, stream>>>(x, xt);
    wt_prep<<<dim3(4, CO), 256, 0, stream>>>(w, wt);
    conv_main<<<dim3(32, NB), 256, 65536, stream>>>(xt, wt, bias, out);
}

// Round 9
// 310.206 us; speedup vs baseline: 1.1781x; 1.0277x over previous
//
#include <hip/hip_runtime.h>

// Conv1d via implicit GEMM on MFMA f16.
// out[b,co,t] = bias[co] + sum_{ci,m} w[co,ci,m] * x[b,ci,t-32+m], t in [0,4032)
// R8 (resubmit; bench never ran — acquisition timeout):
//     merged k=64 body (one barrier per tap m), [chunk][row] LDS layouts
//     (conflict-free without swizzles, ~1 VALU per fragment address),
//     W ring = 3 pairs x 16 KB, vmcnt(4) certification, post-barrier
//     fragment prefetch pinned with sched_barrier(0).

typedef _Float16 f16;
typedef _Float16 f16x8 __attribute__((ext_vector_type(8)));
typedef float f32x4 __attribute__((ext_vector_type(4)));

#define NB   16
#define CI   128
#define CO   128
#define LIN  4096
#define KW   129
#define TOUT 4032
#define UPAD 4224                 // xT rows per (b, p, chunk)
#define XT_BYTES ((size_t)NB * 2 * 8 * UPAD * 16)   // 17,301,504
#define WLDS 32768                // W ring base in LDS (after 32 KB X tile)

__device__ __forceinline__ void gld16(void* lds, const void* g) {
    __builtin_amdgcn_global_load_lds(
        (const __attribute__((address_space(1))) unsigned int*)g,
        (__attribute__((address_space(3))) unsigned int*)lds,
        16, 0, 0);
}

// ---- pre-pass 1: x (f32, [b][ci][l]) -> xt2 (f16, [b][p][c8][u] 16B units) --------
// u = l + 32; rows u<32 and u>=4128 are zero. Unit (b,p,c,u) holds
// x[b][ci = p*64 + c*8 .. +8][u-32] as 8 f16.
__global__ __launch_bounds__(256) void xt_prep(const float* __restrict__ x,
                                               f16* __restrict__ xt) {
    __shared__ float tile[128][33];           // [ci][lcol], +1 pad
    const int b  = blockIdx.y;
    const int u0 = blockIdx.x * 32;
    const int l0 = u0 - 32;
    const int tid = threadIdx.x;
    const int col = tid & 31;
    const int cib = tid >> 5;                 // 0..7
#pragma unroll
    for (int r = 0; r < 16; ++r) {
        int ci = cib + r * 8;
        int l  = l0 + col;
        float v = 0.f;
        if (l >= 0 && l < LIN) v = x[((size_t)b * CI + ci) * LIN + l];
        tile[ci][col] = v;
    }
    __syncthreads();
#pragma unroll
    for (int it = 0; it < 2; ++it) {
        int idx   = tid + it * 256;           // 0..511 = 16 chunks * 32 rows
        int chunk = idx >> 5;                 // 0..15  (= p*8 + c)
        int ur    = idx & 31;
        f16x8 v;
#pragma unroll
        for (int j = 0; j < 8; ++j) v[j] = (f16)tile[chunk * 8 + j][ur];
        size_t unit = ((size_t)b * 16 + chunk) * UPAD + (u0 + ur);
        *(f16x8*)(&xt[unit * 8]) = v;
    }
}

// ---- pre-pass 2: w (f32, [co][ci][m]) -> wt2 (f16, [kk][c4][co] 16B units) -------
// kk = m*4 + cic. Unit (kk,c,co) holds w[co][ci=(kk&3)*32 + c*8 .. +8][kk>>2].
__global__ __launch_bounds__(256) void wt_prep(const float* __restrict__ w,
                                               f16* __restrict__ wt) {
    __shared__ float tile[32][132];           // [ci_local][m], padded
    const int cic = blockIdx.x;               // 0..3
    const int co  = blockIdx.y;               // 0..127
    const int ci0 = cic * 32;
    const int tid = threadIdx.x;
    for (int it = 0; it < 17; ++it) {
        int idx = tid + it * 256;
        if (idx < 32 * 129) {
            int i = idx / 129;
            int m = idx - i * 129;
            tile[i][m] = w[(size_t)co * (CI * KW) + (size_t)(ci0 + i) * KW + m];
        }
    }
    __syncthreads();
    for (int it = 0; it < 3; ++it) {
        int idx = tid + it * 256;
        if (idx < 129 * 4) {
            int m = idx >> 2;
            int c = idx & 3;
            int kk = m * 4 + cic;
            f16x8 v;
#pragma unroll
            for (int j = 0; j < 8; ++j) v[j] = (f16)tile[c * 8 + j][m];
            *(f16x8*)(&wt[(size_t)kk * 4096 + c * 1024 + co * 8]) = v;
        }
    }
}

// ---- main kernel: 128co x 128t per block, 4 waves of 64x64, k=64 per body --------
// LDS: X tile  [8 chunks][256 rows][16B] = 32 KB
//      W ring  3 pairs x (2 chunks x [4][128][16B]) = 48 KB      (80 KB total)
__global__ __launch_bounds__(256, 2) void conv_main(
    const f16* __restrict__ xt, const f16* __restrict__ wt,
    const float* __restrict__ bias, float* __restrict__ out)
{
    extern __shared__ char smem[];
    const int tid  = threadIdx.x;
    const int lane = tid & 63;
    const int wid  = tid >> 6;
    const int l15  = lane & 15;
    const int l4   = lane >> 4;
    const int wco  = (wid >> 1) << 6;     // 0 / 64
    const int wtt  = (wid & 1) << 6;      // 0 / 64

    const int tt = blockIdx.x;            // 0..31 (t-tile)
    const int b  = blockIdx.y;            // 0..15
    const int u0 = tt << 7;

    const char* wbase = (const char*)wt;
    char* wring = smem + WLDS;

    // loop-invariant fragment offsets
    // af: addr = pair_base + q*8192 + aoff[ct];  aoff = l4*2048 + co_row*16
    int aoff[4];
#pragma unroll
    for (int ct = 0; ct < 4; ++ct)
        aoff[ct] = l4 * 2048 + (wco + ct * 16 + l15) * 16;
    // bf: addr = qb[q] + xoff[st] + m*16
    int qb[2];
#pragma unroll
    for (int q = 0; q < 2; ++q) qb[q] = (q * 4 + l4) * 4096;
    int xoff[4];
#pragma unroll
    for (int st = 0; st < 4; ++st)
        xoff[st] = (wtt + st * 16 + l15) * 16;

    f32x4 acc[4][4];
#pragma unroll
    for (int i = 0; i < 4; ++i)
#pragma unroll
        for (int j = 0; j < 4; ++j)
            acc[i][j] = (f32x4){0.f, 0.f, 0.f, 0.f};

    f16x8 afA[2][4], bfA[2][4], afB[2][4], bfB[2][4];

    for (int p = 0; p < 2; ++p) {         // ci-halves
        const int pbase = 2 * p;

        if (p) {                          // drain LDS reads before restaging X
            asm volatile("s_waitcnt lgkmcnt(0)" ::: "memory");
            __builtin_amdgcn_s_barrier();
        }
        // stage X half: chunk i rows u0..u0+255 -> LDS [i][row]
        const char* xph = (const char*)xt +
            (((size_t)b * 16 + p * 8) * UPAD + u0) * 16;
#pragma unroll
        for (int i = 0; i < 8; ++i)
            gld16(smem + tid * 16 + i * 4096, xph + (size_t)i * (UPAD * 16) + tid * 16);
        // stage W pairs for t=0 (kk = pbase..pbase+1) and t=1 (kk = 4+pbase..)
        {
            const char* ws0 = wbase + (size_t)pbase * 8192;
            gld16(wring + tid * 16,         ws0 + tid * 16);
            gld16(wring + 4096 + tid * 16,  ws0 + 4096 + tid * 16);
            gld16(wring + 8192 + tid * 16,  ws0 + 8192 + tid * 16);
            gld16(wring + 12288 + tid * 16, ws0 + 12288 + tid * 16);
            const char* ws1 = wbase + (size_t)(4 + pbase) * 8192;
            gld16(wring + 16384 + tid * 16, ws1 + tid * 16);
            gld16(wring + 20480 + tid * 16, ws1 + 4096 + tid * 16);
            gld16(wring + 24576 + tid * 16, ws1 + 8192 + tid * 16);
            gld16(wring + 28672 + tid * 16, ws1 + 12288 + tid * 16);
        }
        asm volatile("s_waitcnt vmcnt(4)" ::: "memory");  // X + pair0 resident
        __builtin_amdgcn_s_barrier();
        __builtin_amdgcn_sched_barrier(0);

        // preload fragments for t = 0 from pair 0
#pragma unroll
        for (int q = 0; q < 2; ++q) {
#pragma unroll
            for (int ct = 0; ct < 4; ++ct)
                afA[q][ct] = *(const f16x8*)(wring + q * 8192 + aoff[ct]);
#pragma unroll
            for (int st = 0; st < 4; ++st)
                bfA[q][st] = *(const f16x8*)(smem + qb[q] + xoff[st]);
        }

        int rpF = 1, rpD = 2;             // ring-pair indices for t+1 reads / t+2 DMA

        // body(t): DMA pair t+2, certify pair t+1, read frags t+1, MFMA t.
        auto body = [&](int t, f16x8 (&afC)[2][4], f16x8 (&bfC)[2][4],
                               f16x8 (&afN)[2][4], f16x8 (&bfN)[2][4]) {
            const bool issue = (t + 2 <= 128);
            if (issue) {
                const char* wsrc = wbase + (size_t)(4 * (t + 2) + pbase) * 8192;
                char* dst = wring + rpD * 16384;
                gld16(dst + tid * 16,         wsrc + tid * 16);
                gld16(dst + 4096 + tid * 16,  wsrc + 4096 + tid * 16);
                gld16(dst + 8192 + tid * 16,  wsrc + 8192 + tid * 16);
                gld16(dst + 12288 + tid * 16, wsrc + 12288 + tid * 16);
                asm volatile("s_waitcnt vmcnt(4)" ::: "memory");  // pair t+1 done
            } else {
                asm volatile("s_waitcnt vmcnt(0)" ::: "memory");
            }
            __builtin_amdgcn_s_barrier();
            __builtin_amdgcn_sched_barrier(0);   // no reads above certification
            if (t + 1 <= 128) {
                const int mn = (t + 1) * 16;
                const char* wl = wring + rpF * 16384;
#pragma unroll
                for (int q = 0; q < 2; ++q) {
#pragma unroll
                    for (int ct = 0; ct < 4; ++ct)
                        afN[q][ct] = *(const f16x8*)(wl + q * 8192 + aoff[ct]);
#pragma unroll
                    for (int st = 0; st < 4; ++st)
                        bfN[q][st] = *(const f16x8*)(smem + qb[q] + xoff[st] + mn);
                }
            }
#pragma unroll
            for (int q = 0; q < 2; ++q)
#pragma unroll
                for (int ct = 0; ct < 4; ++ct)
#pragma unroll
                    for (int st = 0; st < 4; ++st)
                        acc[ct][st] = __builtin_amdgcn_mfma_f32_16x16x32_f16(
                            afC[q][ct], bfC[q][st], acc[ct][st], 0, 0, 0);
            rpF = (rpF == 2) ? 0 : rpF + 1;
            rpD = (rpD == 2) ? 0 : rpD + 1;
        };

        for (int t2 = 0; t2 < 128; t2 += 2) {
            body(t2,     afA, bfA, afB, bfB);
            body(t2 + 1, afB, bfB, afA, bfA);
        }
        body(128, afA, bfA, afB, bfB);    // tail (fills B unused)
    }

    // epilogue: D[row=co_local][col=t_local]; row=(l>>4)*4+reg, col=l&15
#pragma unroll
    for (int ct = 0; ct < 4; ++ct) {
#pragma unroll
        for (int r = 0; r < 4; ++r) {
            int co = wco + ct * 16 + l4 * 4 + r;
            float bv = bias[co];
            float* orow = out + ((size_t)b * CO + co) * TOUT;
#pragma unroll
            for (int st = 0; st < 4; ++st) {
                int t = u0 + wtt + st * 16 + l15;
                if (t < TOUT) orow[t] = acc[ct][st][r] + bv;
            }
        }
    }
}

extern "C" void kernel_launch(void* const* d_in, const int* in_sizes, int n_in,
                              void* d_out, int out_size, void* d_ws, size_t ws_size,
                              hipStream_t stream) {
    const float* x    = (const float*)d_in[0];
    const float* w    = (const float*)d_in[1];
    const float* bias = (const float*)d_in[2];
    float* out = (float*)d_out;

    f16* xt = (f16*)d_ws;                              // 17,301,504 B
    f16* wt = (f16*)((char*)d_ws + XT_BYTES);          //  4,227,072 B

    xt_prep<<<dim3(UPAD / 32, NB), 256, 0, stream>>>(x, xt);
    wt_prep<<<dim3(4, CO), 256, 0, stream>>>(w, wt);
    conv_main<<<dim3(32, NB), 256, 81920, stream>>>(xt, wt, bias, out);
}